// Round 5
// baseline (1466.655 us; speedup 1.0000x reference)
//
#include <hip/hip_runtime.h>
#include <stdint.h>

#define DIM 2048
#define HID 5632
#define SEQ 8192
#define NW3 (3*HID)            // 16896
#define CONV 4
#define PLDC 8448              // fp32 stride of partial buffer aliased over G rows

typedef __attribute__((ext_vector_type(8))) __bf16 bf16x8;
typedef __attribute__((ext_vector_type(4))) float f32x4;
typedef __attribute__((ext_vector_type(16))) float f32x16;
typedef __attribute__((ext_vector_type(4))) uint16_t u16x4;

__device__ __forceinline__ uint16_t f2bf(float f) {
  union { float f; uint32_t u; } v; v.f = f;
  return (uint16_t)((v.u + 0x7FFFu + ((v.u >> 16) & 1u)) >> 16);
}
__device__ __forceinline__ float bf2f(uint16_t h) {
  union { uint32_t u; float f; } v; v.u = ((uint32_t)h) << 16;
  return v.f;
}

// ---------------- fp32 -> bf16 conversion (vectorized x4) ----------------
__global__ void cvt4_kernel(const float* __restrict__ src, uint16_t* __restrict__ dst, int n4) {
  int i = blockIdx.x * blockDim.x + threadIdx.x;
  if (i >= n4) return;
  float4 v = ((const float4*)src)[i];
  ushort4 o;
  o.x = f2bf(v.x); o.y = f2bf(v.y); o.z = f2bf(v.z); o.w = f2bf(v.w);
  ((ushort4*)dst)[i] = o;
}

__device__ __forceinline__ void load_lds16(const void* g, void* l) {
  __builtin_amdgcn_global_load_lds(
      (__attribute__((address_space(1))) void*)g,
      (__attribute__((address_space(3))) void*)l, 16, 0, 0);
}

// ---------------- 128x256 / BK=32 / 3-buf bf16 GEMM: C = A(M,K;LDA)*B(N,K;LDB)^T
// r4 geometry (2 blocks/CU, 16 waves/CU — the proven occupancy win) with the
// inner MFMA switched 16x16x32 -> 32x32x16: per-wave 64x64 = 2x2 of 32x32,
// 8 MFMA/tile (was 16) at higher FLOP/cy (m119: 2495 vs ~2100 TF ceiling),
// identical LDS bytes and identical read uniformity (8 lanes per bank-position
// -> conflict-free, HW-verified 0 conflicts r1-r4 for the same profile).
// A/B frag: row=lane&31, k=(lane>>5)*8+j. C/D: col=lane&31,
// row=(reg&3)+8*(reg>>2)+4*(lane>>5) [m74/m101].
// LDS per buf: A[128][32] + B[256][32] bf16, XOR swizzle
//   phys_kgroup = kgroup ^ ((row>>1)&3)  (kgroup = 8-elem slice index 0..3)
// inverse-swizzled global source + swizzled ds_read; gload_lds dest linear.
// Per K-tile: { 8 ds_read | STAGE(t+2): 3 loads | lgkmcnt(0)+PIN |
//   setprio(1) 8 MFMA setprio(0) | vmcnt(3) | barrier } — vmcnt counted,
// never 0 in loop (STAGE(t+1) landed, STAGE(t+2) in flight).
// OUT_MODE: 0 = fp32 store to C; 1 = bf16 store to C;
//           2 = split-K dual store: z==0 -> fp32 C2 (LDC2), z==1 -> fp32 C.
template<int LDA, int LDB, int LDC, int LDC2, int KLEN, int OUT_MODE>
__global__ __launch_bounds__(512, 4)
void gemm128(const uint16_t* __restrict__ A, const uint16_t* __restrict__ B,
             void* __restrict__ C, float* __restrict__ C2, int nbx)
{
  __shared__ alignas(16) uint16_t As[3][128][32];
  __shared__ alignas(16) uint16_t Bs[3][256][32];
  constexpr int NT = KLEN / 32;

  const int tid  = threadIdx.x;
  const int wave = tid >> 6;
  const int lane = tid & 63;

  // bijective XCD-aware swizzle (m204); grid.x divisible by 8 in all uses
  const int nwg = (int)gridDim.x;
  const int bid = (int)blockIdx.x;
  const int qq  = nwg >> 3, rr = nwg & 7;
  const int xcd = bid & 7, loc = bid >> 3;
  const int swz = (xcd < rr ? xcd*(qq+1) : rr*(qq+1) + (xcd-rr)*qq) + loc;
  const int row0 = (swz % nbx) * 128;
  const int col0 = (swz / nbx) * 256;

  const uint16_t* Ab = A + (size_t)blockIdx.z * KLEN;   // split-K slice
  const uint16_t* Bb = B + (size_t)blockIdx.z * KLEN;

  const int wr = wave >> 2;          // 0..1 -> rows wr*64..
  const int wc = wave & 3;           // 0..3 -> cols wc*64..
  const int r32 = lane & 31;
  const int kg  = lane >> 5;                 // k-group half (0/1)
  const int sxor = (r32 >> 1) & 3;           // swizzle term (row>>1)&3
  const int eo0 = ((0*2 + kg) ^ sxor) * 8;   // ks=0 elem offset (swizzled)
  const int eo1 = ((1*2 + kg) ^ sxor) * 8;   // ks=1 elem offset (swizzled)

  // staging: granule g holds logical row g>>2, k-group (g&3)^((row>>1)&3)
  // (inverse swizzle at the global source; LDS dest stays linear)
  size_t offA, offB0, offB1;
  {
    const int ra = tid >> 2,        ka = (tid & 3) ^ ((ra >> 1) & 3);
    const int rb0 = tid >> 2,       kb0 = (tid & 3) ^ ((rb0 >> 1) & 3);
    const int g1 = 512 + tid;
    const int rb1 = g1 >> 2,        kb1 = (g1 & 3) ^ ((rb1 >> 1) & 3);
    offA  = (size_t)(row0 + ra)*LDA + ka*8;
    offB0 = (size_t)(col0 + rb0)*LDB + kb0*8;
    offB1 = (size_t)(col0 + rb1)*LDB + kb1*8;
  }

#define STAGE(kt,buf) do {                                                  \
    const size_t ko_ = (size_t)(kt)*32;                                     \
    load_lds16(Ab + offA  + ko_, &As[(buf)][wave*16][0]);                   \
    load_lds16(Bb + offB0 + ko_, &Bs[(buf)][wave*16][0]);                   \
    load_lds16(Bb + offB1 + ko_, &Bs[(buf)][128 + wave*16][0]);             \
  } while (0)
#define PIN() __builtin_amdgcn_sched_barrier(0)

  f32x16 acc[2][2];
  #pragma unroll
  for (int i = 0; i < 2; ++i)
    #pragma unroll
    for (int j = 0; j < 2; ++j)
      #pragma unroll
      for (int e = 0; e < 16; ++e) acc[i][j][e] = 0.f;

  // prologue: tile0 -> buf0, tile1 -> buf1
  STAGE(0, 0);
  {
    const int t1 = (NT > 1) ? 1 : 0;
    STAGE(t1, 1);
  }
  asm volatile("s_waitcnt vmcnt(3)" ::: "memory");   // tile0 landed
  __builtin_amdgcn_s_barrier();
  PIN();

  int c = 0;
  #pragma unroll 1
  for (int t = 0; t < NT; ++t) {
    const int tn2 = (t+2 < NT) ? t+2 : NT-1;   // clamped (dummy) at tail
    int cs = c + 2; if (cs >= 3) cs -= 3;      // buf for tile t+2

    bf16x8 a0[2], a1[2], b0[2], b1[2];   // [b] for ks=0 / ks=1
    #pragma unroll
    for (int b = 0; b < 2; ++b) {
      a0[b] = *(const bf16x8*)&As[c][wr*64 + b*32 + r32][eo0];
      a1[b] = *(const bf16x8*)&As[c][wr*64 + b*32 + r32][eo1];
      b0[b] = *(const bf16x8*)&Bs[c][wc*64 + b*32 + r32][eo0];
      b1[b] = *(const bf16x8*)&Bs[c][wc*64 + b*32 + r32][eo1];
    }
    STAGE(tn2, cs);
    PIN();
    asm volatile("s_waitcnt lgkmcnt(0)" ::: "memory");
    PIN();
    __builtin_amdgcn_s_setprio(1);
    #pragma unroll
    for (int i = 0; i < 2; ++i)
      #pragma unroll
      for (int j = 0; j < 2; ++j)
        acc[i][j] = __builtin_amdgcn_mfma_f32_32x32x16_bf16(a0[i], b0[j], acc[i][j], 0, 0, 0);
    #pragma unroll
    for (int i = 0; i < 2; ++i)
      #pragma unroll
      for (int j = 0; j < 2; ++j)
        acc[i][j] = __builtin_amdgcn_mfma_f32_32x32x16_bf16(a1[i], b1[j], acc[i][j], 0, 0, 0);
    __builtin_amdgcn_s_setprio(0);
    asm volatile("s_waitcnt vmcnt(3)" ::: "memory");  // STAGE(t+1) landed; t+2 in flight
    __builtin_amdgcn_s_barrier();
    PIN();

    c += 1; if (c >= 3) c = 0;
  }
#undef STAGE
#undef PIN

  // epilogue: 32x32 C/D layout: col=lane&31, row=(reg&3)+8*(reg>>2)+4*(lane>>5)
  #pragma unroll
  for (int i = 0; i < 2; ++i)
    #pragma unroll
    for (int j = 0; j < 2; ++j) {
      const int rbase = row0 + wr*64 + i*32 + 4*kg;
      const int c_    = col0 + wc*64 + j*32 + r32;
      #pragma unroll
      for (int reg = 0; reg < 16; ++reg) {
        const int r_ = rbase + (reg & 3) + 8*(reg >> 2);
        const float v = acc[i][j][reg];
        if (OUT_MODE == 1) {
          ((uint16_t*)C)[(size_t)r_*LDC + c_] = f2bf(v);
        } else if (OUT_MODE == 2) {
          if (blockIdx.z == 0) C2[(size_t)r_*LDC2 + c_] = v;
          else                 ((float*)C)[(size_t)r_*LDC + c_] = v;
        } else {
          ((float*)C)[(size_t)r_*LDC + c_] = v;
        }
      }
    }
}

// ---------------- merge split-K partial: out += P (P strided PLDC) ----------------
__global__ void addP_kernel(float* __restrict__ out, const float* __restrict__ P, int n4) {
  int i = blockIdx.x * blockDim.x + threadIdx.x;
  if (i >= n4) return;
  int r  = i >> 9;             // DIM/4 = 512 float4 per row
  int c4 = i & 511;
  float4 a = ((float4*)out)[i];
  float4 b = *(const float4*)&P[(size_t)r*PLDC + c4*4];
  a.x += b.x; a.y += b.y; a.z += b.z; a.w += b.w;
  ((float4*)out)[i] = a;
}

// ---------------- segment helpers ----------------
// G layout per local row r (stride NW3): [0,HID)=w0, [HID,2HID)=z_pre, [2HID,3HID)=tilde_h

__device__ __forceinline__ void seg_info(const int* cuv, int ns, int t, int& ss, bool& st) {
  ss = 0; st = false;
  for (int i=0;i<ns;i++) { int cv = cuv[i]; if (cv<=t && cv>ss) ss=cv; if (cv==t) st=true; }
}

// ---------------- scan pass A: per-chunk conv+sigmoid+local scan (VEC=4) ----------------
// chunk is runtime (32 preferred: 2x blocks, half serial chain vs 64).
__global__ void scan_chunk(const uint16_t* __restrict__ G, int qstart,
                           const uint16_t* __restrict__ zprev,
                           const float* __restrict__ convw,
                           const int* __restrict__ cu, int ncu, int chunk,
                           float* __restrict__ Ach, float* __restrict__ Bch)
{
  const int h0 = (blockIdx.x * blockDim.x + threadIdx.x) * 4;   // 11*128*4 = 5632
  const int c  = blockIdx.y;
  const uint16_t* Z  = G + HID;
  const uint16_t* TH = G + 2*HID;
  float4 wv[4];
  #pragma unroll
  for (int j=0;j<4;j++) wv[j] = ((const float4*)convw)[h0+j];
  int cuv[8];
  int ns = ncu - 1; if (ns > 8) ns = 8;
  for (int i=0;i<ns;i++) cuv[i] = cu[i];
  const int r0 = c * chunk;
  const int t0 = qstart + r0;
  float z1[4], z2[4], z3[4];
  if (c == 0) {
    u16x4 a1 = *(const u16x4*)&zprev[2*HID + h0];
    u16x4 a2 = *(const u16x4*)&zprev[1*HID + h0];
    u16x4 a3 = *(const u16x4*)&zprev[0*HID + h0];
    #pragma unroll
    for (int j=0;j<4;j++) {
      z1[j] = (t0-1 >= 0) ? bf2f(a1[j]) : 0.f;
      z2[j] = (t0-2 >= 0) ? bf2f(a2[j]) : 0.f;
      z3[j] = (t0-3 >= 0) ? bf2f(a3[j]) : 0.f;
    }
  } else {
    u16x4 a1 = *(const u16x4*)&Z[(size_t)(r0-1)*NW3 + h0];
    u16x4 a2 = *(const u16x4*)&Z[(size_t)(r0-2)*NW3 + h0];
    u16x4 a3 = *(const u16x4*)&Z[(size_t)(r0-3)*NW3 + h0];
    #pragma unroll
    for (int j=0;j<4;j++) { z1[j]=bf2f(a1[j]); z2[j]=bf2f(a2[j]); z3[j]=bf2f(a3[j]); }
  }
  float Aacc[4] = {1.f,1.f,1.f,1.f};
  float Bacc[4] = {0.f,0.f,0.f,0.f};
  u16x4 zv = *(const u16x4*)&Z[(size_t)r0*NW3 + h0];
  u16x4 tv = *(const u16x4*)&TH[(size_t)r0*NW3 + h0];
  for (int r = r0; r < r0 + chunk; ++r) {
    const int rn = (r+1 < r0+chunk) ? r+1 : r;   // clamped prefetch (in-bounds)
    u16x4 zn = *(const u16x4*)&Z[(size_t)rn*NW3 + h0];
    u16x4 tn = *(const u16x4*)&TH[(size_t)rn*NW3 + h0];
    const int t = qstart + r;
    int ss; bool st;
    seg_info(cuv, ns, t, ss, st);
    const bool k1 = (t-1 >= ss), k2 = (t-2 >= ss), k3 = (t-3 >= ss);
    #pragma unroll
    for (int j=0;j<4;j++) {
      const float zc0 = bf2f(zv[j]);
      float s = zc0*wv[j].w;
      if (k1) s += z1[j]*wv[j].z;
      if (k2) s += z2[j]*wv[j].y;
      if (k3) s += z3[j]*wv[j].x;
      const float zc = 1.f/(1.f + __expf(-s));
      const float a = st ? 0.f : (1.f - zc);
      const float b = zc * bf2f(tv[j]);
      Aacc[j] *= a;
      Bacc[j] = a*Bacc[j] + b;
      z3[j] = z2[j]; z2[j] = z1[j]; z1[j] = zc0;
    }
    zv = zn; tv = tn;
  }
  *(float4*)&Ach[(size_t)c*HID + h0] = make_float4(Aacc[0],Aacc[1],Aacc[2],Aacc[3]);
  *(float4*)&Bch[(size_t)c*HID + h0] = make_float4(Bacc[0],Bacc[1],Bacc[2],Bacc[3]);
}

// ---------------- scan pass B: combine chunks (float4, prefetch); Hin over Ach ----------------
__global__ void scan_combine(float* __restrict__ Ach, const float* __restrict__ Bch,
                             float* __restrict__ Sc, int first, int nchunk)
{
  const int h0 = (blockIdx.x * blockDim.x + threadIdx.x) * 4;
  float4 s;
  if (first) s = make_float4(0.f,0.f,0.f,0.f);
  else       s = *(const float4*)&Sc[h0];
  float4 a = *(const float4*)&Ach[h0];
  float4 b = *(const float4*)&Bch[h0];
  for (int c = 0; c < nchunk; ++c) {
    const int cn = (c+1 < nchunk) ? c+1 : c;
    float4 an = *(const float4*)&Ach[(size_t)cn*HID + h0];
    float4 bn = *(const float4*)&Bch[(size_t)cn*HID + h0];
    *(float4*)&Ach[(size_t)c*HID + h0] = s;   // state entering chunk c (Hin)
    s.x = a.x*s.x + b.x;
    s.y = a.y*s.y + b.y;
    s.z = a.z*s.z + b.z;
    s.w = a.w*s.w + b.w;
    a = an; b = bn;
  }
  *(float4*)&Sc[h0] = s;
}

// ---------------- scan pass C: fixup + h*silu(w0) (VEC=4), hh in place over TH ----------------
__global__ void scan_final(uint16_t* __restrict__ G, int qstart,
                           const uint16_t* __restrict__ zprev,
                           const float* __restrict__ convw,
                           const int* __restrict__ cu, int ncu, int chunk,
                           const float* __restrict__ Hin)
{
  const int h0 = (blockIdx.x * blockDim.x + threadIdx.x) * 4;
  const int c  = blockIdx.y;
  const uint16_t* W0 = G;
  const uint16_t* Z  = G + HID;
  uint16_t*       TH = G + 2*HID;     // read th, then overwrite with hh
  float4 wv[4];
  #pragma unroll
  for (int j=0;j<4;j++) wv[j] = ((const float4*)convw)[h0+j];
  int cuv[8];
  int ns = ncu - 1; if (ns > 8) ns = 8;
  for (int i=0;i<ns;i++) cuv[i] = cu[i];
  const int r0 = c * chunk;
  const int t0 = qstart + r0;
  float z1[4], z2[4], z3[4];
  if (c == 0) {
    u16x4 a1 = *(const u16x4*)&zprev[2*HID + h0];
    u16x4 a2 = *(const u16x4*)&zprev[1*HID + h0];
    u16x4 a3 = *(const u16x4*)&zprev[0*HID + h0];
    #pragma unroll
    for (int j=0;j<4;j++) {
      z1[j] = (t0-1 >= 0) ? bf2f(a1[j]) : 0.f;
      z2[j] = (t0-2 >= 0) ? bf2f(a2[j]) : 0.f;
      z3[j] = (t0-3 >= 0) ? bf2f(a3[j]) : 0.f;
    }
  } else {
    u16x4 a1 = *(const u16x4*)&Z[(size_t)(r0-1)*NW3 + h0];
    u16x4 a2 = *(const u16x4*)&Z[(size_t)(r0-2)*NW3 + h0];
    u16x4 a3 = *(const u16x4*)&Z[(size_t)(r0-3)*NW3 + h0];
    #pragma unroll
    for (int j=0;j<4;j++) { z1[j]=bf2f(a1[j]); z2[j]=bf2f(a2[j]); z3[j]=bf2f(a3[j]); }
  }
  float state[4];
  {
    float4 hv = *(const float4*)&Hin[(size_t)c*HID + h0];
    state[0]=hv.x; state[1]=hv.y; state[2]=hv.z; state[3]=hv.w;
  }
  u16x4 zv = *(const u16x4*)&Z[(size_t)r0*NW3 + h0];
  u16x4 tv = *(const u16x4*)&TH[(size_t)r0*NW3 + h0];
  u16x4 wvv = *(const u16x4*)&W0[(size_t)r0*NW3 + h0];
  for (int r = r0; r < r0 + chunk; ++r) {
    const int rn = (r+1 < r0+chunk) ? r+1 : r;
    u16x4 zn = *(const u16x4*)&Z[(size_t)rn*NW3 + h0];
    u16x4 tn = *(const u16x4*)&TH[(size_t)rn*NW3 + h0];
    u16x4 wn = *(const u16x4*)&W0[(size_t)rn*NW3 + h0];
    const int t = qstart + r;
    int ss; bool st;
    seg_info(cuv, ns, t, ss, st);
    const bool k1 = (t-1 >= ss), k2 = (t-2 >= ss), k3 = (t-3 >= ss);
    u16x4 outv;
    #pragma unroll
    for (int j=0;j<4;j++) {
      const float zc0 = bf2f(zv[j]);
      float s = zc0*wv[j].w;
      if (k1) s += z1[j]*wv[j].z;
      if (k2) s += z2[j]*wv[j].y;
      if (k3) s += z3[j]*wv[j].x;
      const float zc = 1.f/(1.f + __expf(-s));
      const float a = st ? 0.f : (1.f - zc);
      const float b = zc * bf2f(tv[j]);
      state[j] = a*state[j] + b;
      const float w0v = bf2f(wvv[j]);
      const float silu = w0v / (1.f + __expf(-w0v));
      outv[j] = f2bf(state[j] * silu);
      z3[j] = z2[j]; z2[j] = z1[j]; z1[j] = zc0;
    }
    *(u16x4*)&TH[(size_t)r*NW3 + h0] = outv;
    zv = zn; tv = tn; wvv = wn;
  }
}

// ---------------- save last 3 z-rows for next segment's conv taps (ushort4) ----------------
__global__ void save_ztail(const uint16_t* __restrict__ G, uint16_t* __restrict__ zprev, int qrows) {
  int i4 = (blockIdx.x * blockDim.x + threadIdx.x) * 4;
  if (i4 >= 3*HID) return;
  int j = i4 / HID;        // HID%4==0 so a ushort4 never straddles rows
  int h = i4 - j*HID;
  *(u16x4*)&zprev[i4] = *(const u16x4*)&G[(size_t)(qrows-3+j)*NW3 + HID + h];
}

// ---------------- launcher ----------------
extern "C" void kernel_launch(void* const* d_in, const int* in_sizes, int n_in,
                              void* d_out, int out_size, void* d_ws, size_t ws_size,
                              hipStream_t stream) {
  const float* x     = (const float*)d_in[0];
  const int*   cu    = (const int*)d_in[1];
  const float* w_w   = (const float*)d_in[2];
  const float* wz_w  = (const float*)d_in[3];
  const float* wh_w  = (const float*)d_in[4];
  const float* wo_w  = (const float*)d_in[5];
  const float* convw = (const float*)d_in[6];
  const int ncu = in_sizes[1];
  float* out = (float*)d_out;

  // ---- tier selection: largest (qrows, smallest chunk) that fits ws ----
  // per-row: G 33792 + xseg 4096 = 37888; Ach+Bch = (qrows/chunk)*HID*8 total
  auto need = [](long long q, long long ch) -> unsigned long long {
    return 92331008ull + (unsigned long long)(q*37888ll) +
           (unsigned long long)((q/ch)*(long long)HID*8ll);
  };
  int qrows, chunk;
  if      (ws_size >= need(8192,32)) { qrows = 8192; chunk = 32; }
  else if (ws_size >= need(8192,64)) { qrows = 8192; chunk = 64; }
  else if (ws_size >= need(4096,32)) { qrows = 4096; chunk = 32; }
  else if (ws_size >= need(4096,64)) { qrows = 4096; chunk = 64; }
  else if (ws_size >= need(2048,32)) { qrows = 2048; chunk = 32; }
  else                               { qrows = 2048; chunk = 64; }
  const int nq = SEQ / qrows;
  const int nchunk = qrows / chunk;

  // ---- workspace layout ----
  char* p = (char*)d_ws;
  uint16_t* w3b  = (uint16_t*)p; p += (size_t)NW3*DIM*2;       // 69.2 MB
  uint16_t* wob  = (uint16_t*)p; p += (size_t)DIM*HID*2;       // 23.1 MB
  float*    Sc   = (float*)p;    p += (size_t)HID*4;
  uint16_t* zprev= (uint16_t*)p; p += (size_t)3*HID*2;
  uint16_t* xseg = (uint16_t*)p; p += (size_t)qrows*DIM*2;
  uint16_t* G    = (uint16_t*)p; p += (size_t)qrows*NW3*2;
  float*    Ach  = (float*)p;    p += (size_t)nchunk*HID*4;    // doubles as Hin
  float*    Bch  = (float*)p;    p += (size_t)nchunk*HID*4;

  // ---- weight conversions (once) ----
  {
    int n4 = HID*DIM/4;
    cvt4_kernel<<<(n4+255)/256, 256, 0, stream>>>(w_w,  w3b, n4);
    cvt4_kernel<<<(n4+255)/256, 256, 0, stream>>>(wz_w, w3b + (size_t)HID*DIM, n4);
    cvt4_kernel<<<(n4+255)/256, 256, 0, stream>>>(wh_w, w3b + (size_t)2*HID*DIM, n4);
    n4 = DIM*HID/4;
    cvt4_kernel<<<(n4+255)/256, 256, 0, stream>>>(wo_w, wob, n4);
  }

  for (int s = 0; s < nq; ++s) {
    const int qstart = s * qrows;

    // x segment -> bf16
    int n4 = qrows*DIM/4;
    cvt4_kernel<<<(n4+255)/256, 256, 0, stream>>>(x + (size_t)qstart*DIM, xseg, n4);

    // GEMM1: G = xseg @ [w_w;wz_w;wh_w]^T  (M=qrows, N=16896, K=2048)
    {
      const int nbx = qrows / 128;
      gemm128<DIM, DIM, NW3, 0, DIM, 1><<<dim3(nbx * (NW3/256), 1, 1), 512, 0, stream>>>(
          xseg, w3b, G, nullptr, nbx);
    }

    // chunked scan with fused causal conv + gating (h-vectorized x4)
    scan_chunk  <<<dim3(11, nchunk), 128, 0, stream>>>(G, qstart, zprev, convw, cu, ncu, chunk, Ach, Bch);
    scan_combine<<<11, 128, 0, stream>>>(Ach, Bch, Sc, s == 0 ? 1 : 0, nchunk);
    scan_final  <<<dim3(11, nchunk), 128, 0, stream>>>(G, qstart, zprev, convw, cu, ncu, chunk, Ach);

    if (s + 1 < nq)
      save_ztail<<<(3*HID/4+127)/128, 128, 0, stream>>>(G, zprev, qrows);

    // GEMM2: out[qstart:] = hh @ wo^T  (hh aliased over TH, lda=NW3; N=2048, K=5632)
    // split-K=2, no atomics: slice0 -> fp32 partial P aliased over G's dead W0
    // slot (stride PLDC floats), slice1 -> out; then out += P.
    const int nbx2 = qrows / 128;
    float* P = (float*)G;    // W0 region per row: bytes [0,11264) >= 8192 needed
    if (qrows == 8192) {
      gemm128<NW3, HID, DIM, 0, HID, 0><<<dim3(nbx2*(DIM/256), 1, 1), 512, 0, stream>>>(
          G + 2*HID, wob, out + (size_t)qstart*DIM, nullptr, nbx2);
    } else {
      gemm128<NW3, HID, DIM, PLDC, HID/2, 2><<<dim3(nbx2*(DIM/256), 1, 2), 512, 0, stream>>>(
          G + 2*HID, wob, out + (size_t)qstart*DIM, P, nbx2);
      int na = qrows * (DIM/4);
      addP_kernel<<<(na+255)/256, 256, 0, stream>>>(out + (size_t)qstart*DIM, P, na);
    }
  }
}